// Round 8
// baseline (911.718 us; speedup 1.0000x reference)
//
#include <hip/hip_runtime.h>

typedef unsigned int u32;
typedef unsigned long long u64;
typedef __bf16 bf16x8 __attribute__((ext_vector_type(8)));
typedef float f32x4 __attribute__((ext_vector_type(4)));

// Problem constants
#define N_PIX   32768        // 8*64*64 pixels
#define C_DIM   64
#define NE      8192
#define HW      4096         // 64*64
#define BHW     262144       // elements per batch in z (64*4096)
#define ZQ_N    2097152      // 8*64*64*64

// Output layout (flat f32): [0]=loss, [1..2097152]=z_q_out(NCHW), [2097153..]=idx
#define OUT_ZQ_OFF  1
#define OUT_IDX_OFF (1 + ZQ_N)

// Scratch inside d_out's zq region (overwritten by k_final at the end).
// SCR = out + 4 floats (16B aligned). Offsets in 4-byte slots relative to SCR:
#define OFF_ZH    0         // u32[1048576]  : zh bf16 pairs, [pixel][feat]
#define OFF_EH    1048576   // u32[262144]   : eh bf16 pairs, [code][feat]
#define OFF_S     1310720   // f32[32768]    : ||z||^2 exact pairwise
#define OFF_W     1343488   // f32[32768]    : refine window per pixel
#define OFF_CMIN8 1376256   // u32[8*32768]  : per-slice order-encoded coarse min
#define OFF_LIST  1638400   // u32[CAP]      : candidate (pixel<<13|code)
#define CAP       458744

// Workspace (ws) layout:
#define WS_E_OFF  262144   // f32 Etab[8192] after u64 best[32768]
#define WS_C_OFF  294912   // u32 count
#define WS_D_OFF  294916   // u32 done (k_final last-block counter)
#define WS_A_OFF  294920   // f64 loss_acc

// GEMM tiling: block = 256 thr = 4 waves = 2 row-groups x 2 code-groups.
// Each wave: 64 pixel-rows (A in registers), 512 codes streamed from L2.
#define M_BLK   128
#define N_SLICE 1024
#define N_SLICES 8         // NE / N_SLICE
#define LOCBUF  1024       // per-block candidate staging (expected ~24/block)
#define PF      4          // B-stream prefetch ring depth

__device__ __forceinline__ u32 encf(float v) {
    u32 u = __float_as_uint(v);
    return (u & 0x80000000u) ? ~u : (u | 0x80000000u);
}
__device__ __forceinline__ float decf(u32 k) {
    return (k & 0x80000000u) ? __uint_as_float(k ^ 0x80000000u)
                             : __uint_as_float(~k);
}
__device__ __forceinline__ u32 bf16rn(float v) {      // RNE f32->bf16 bits
    u32 u = __float_as_uint(v);
    return (u + 0x7FFFu + ((u >> 16) & 1u)) >> 16;
}
__device__ __forceinline__ int swz(int row, int kg) { // 16B-chunk LDS swizzle
    return row * 8 + (kg ^ (row & 7));
}

// z: exact-pairwise S, Sum|z| -> window, bf16 z in [pixel][feat].
// Also does all one-time inits (best, count/done/loss_acc) — k_init folded in.
__global__ __launch_bounds__(256) void k_prep_z(const float* __restrict__ z,
                                                u32* __restrict__ zh,
                                                float* __restrict__ Sarr,
                                                float* __restrict__ Wp,
                                                u64* __restrict__ best,
                                                u32* __restrict__ count,
                                                u32* __restrict__ done,
                                                double* __restrict__ loss_acc) {
    __shared__ u32 lw[256 * 33];
    const int tid = threadIdx.x;
    const int p   = blockIdx.x * 256 + tid;
    best[p] = ~0ull;
    if (blockIdx.x == 0 && tid == 0) { *count = 0u; *done = 0u; *loss_acc = 0.0; }
    const float* zp = z + (p >> 12) * BHW + (p & 4095);
    float r[8]; float asum = 0.0f; u32 prev = 0;
#pragma unroll
    for (int c = 0; c < C_DIM; ++c) {
        float v  = zp[c * HW];                    // coalesced
        float sq = __fmul_rn(v, v);
        if (c < 8) r[c] = sq; else r[c & 7] = __fadd_rn(r[c & 7], sq);
        asum += fabsf(v);
        u32 hb = bf16rn(v);
        if (c & 1) lw[tid * 33 + (c >> 1)] = prev | (hb << 16);
        else       prev = hb;
    }
    Sarr[p] = __fadd_rn(__fadd_rn(__fadd_rn(r[0], r[1]), __fadd_rn(r[2], r[3])),
                        __fadd_rn(__fadd_rn(r[4], r[5]), __fadd_rn(r[6], r[7])));
    Wp[p]   = 5.0e-5f * asum + 1.0e-4f;   // rigorous bf16 bound + quant slack
    __syncthreads();
#pragma unroll
    for (int j = 0; j < 32; ++j) {        // coalesced u32 writes
        int lg = j * 256 + tid;
        zh[blockIdx.x * 8192 + lg] = lw[(lg >> 5) * 33 + (lg & 31)];
    }
}

// emb: exact-pairwise ||e||^2 table + bf16 codebook [code][feat].
__global__ __launch_bounds__(256) void k_prep_e(const float* __restrict__ emb,
                                                u32* __restrict__ eh,
                                                float* __restrict__ Etab) {
    __shared__ u32 lw[256 * 33];
    const int tid = threadIdx.x;
    const int m   = blockIdx.x * 256 + tid;
    const float* rp = emb + m * C_DIM;
    float r[8]; u32 prev = 0;
#pragma unroll
    for (int c = 0; c < C_DIM; ++c) {
        float v  = rp[c];
        float sq = __fmul_rn(v, v);
        if (c < 8) r[c] = sq; else r[c & 7] = __fadd_rn(r[c & 7], sq);
        u32 hb = bf16rn(v);
        if (c & 1) lw[tid * 33 + (c >> 1)] = prev | (hb << 16);
        else       prev = hb;
    }
    Etab[m] = __fadd_rn(__fadd_rn(__fadd_rn(r[0], r[1]), __fadd_rn(r[2], r[3])),
                        __fadd_rn(__fadd_rn(r[4], r[5]), __fadd_rn(r[6], r[7])));
    __syncthreads();
#pragma unroll
    for (int j = 0; j < 32; ++j) {
        int lg = j * 256 + tid;
        eh[blockIdx.x * 8192 + lg] = lw[(lg >> 5) * 33 + (lg & 31)];
    }
}

// Coarse GEMM, barrier-free K-loop with PF-deep B prefetch ring.
// Round-7 postmortem: compiler stayed at 64/44 VGPR, so depth-1 dbuf left the
// loop latency-bound (MfmaUtil 15%). The explicit PF=4 ring forces ~36 live
// B registers -> 4 iterations of L2 latency cover per wave.
// PASS 0: per-pixel coarse min -> LDS min -> plain store to cmin8[slice][pix]
//         (round-7 counters: 524K global atomicMin = 18.6 MB RMW traffic; now 1 MB).
// PASS 1: threshold = decode(min of 8 slice-mins) + W; collect candidates via
//         LDS staging, one global ticket per block (round-4 lesson).
template <int PASS>
__global__ __launch_bounds__(256, 4) void k_gemm(const uint4* __restrict__ zh4,
                                                 const bf16x8* __restrict__ eh8,
                                                 const float* __restrict__ Etab,
                                                 const float* __restrict__ Wp,
                                                 u32* __restrict__ cmin8,
                                                 u32* __restrict__ count,
                                                 u32* __restrict__ list) {
    __shared__ uint4 a4[M_BLK * 8];      // 16 KB z tile (swizzled 16B chunks)
    __shared__ u32  cm_l[M_BLK];         // pass-0 block-local min
    __shared__ float thr_l[M_BLK];       // pass-1 thresholds
    __shared__ u32 loc_list[LOCBUF];     // 4 KB pass-1 candidate staging
    __shared__ u32 loc_cnt, glob_base;

    const int tid  = threadIdx.x;
    const int lane = tid & 63, w = tid >> 6;
    const int rg_id = w & 1;             // row-group: 64 rows each
    const int cg_id = w >> 1;            // code-group: 512 codes each
    const int q = lane >> 4, c15 = lane & 15;
    const int pixbase   = blockIdx.x * M_BLK;
    const int slicebase = blockIdx.y * N_SLICE;

    // Issue the prefetch ring EARLY (before LDS staging) so it overlaps.
    const int code0 = slicebase + cg_id * 512;
    const bf16x8* bp  = eh8 + (size_t)(code0 + c15) * 8 + q;
    const float*  evp = Etab + code0 + c15;
    bf16x8 pb0[PF], pb1[PF];
    float  pE[PF];
#pragma unroll
    for (int d = 0; d < PF; ++d) {
        pb0[d] = bp[d * 128];
        pb1[d] = bp[d * 128 + 4];
        pE[d]  = evp[d * 16];
    }

    // Stage A tile (coalesced) into swizzled LDS.
#pragma unroll
    for (int it = 0; it < 4; ++it) {
        int idx = it * 256 + tid;                       // = p*8 + kg
        a4[swz(idx >> 3, idx & 7)] = zh4[blockIdx.x * 1024 + idx];
    }
    if (PASS == 0 && tid < M_BLK) cm_l[tid] = 0xFFFFFFFFu;
    if (PASS == 1 && tid < M_BLK) {
        u32 mn = 0xFFFFFFFFu;
#pragma unroll
        for (int s = 0; s < N_SLICES; ++s)
            mn = min(mn, cmin8[s * N_PIX + pixbase + tid]);  // encoded: u32 min ok
        thr_l[tid] = decf(mn) + Wp[pixbase + tid];
    }
    if (PASS == 1 && tid == 0) loc_cnt = 0u;
    __syncthreads();                     // the ONLY pre-flush barrier

    // A fragments: af[rowtile][khalf]; register-resident for the whole K-loop.
    const bf16x8* a_bf = reinterpret_cast<const bf16x8*>(a4);
    bf16x8 af[4][2];
#pragma unroll
    for (int rt = 0; rt < 4; ++rt)
#pragma unroll
        for (int h = 0; h < 2; ++h)
            af[rt][h] = a_bf[swz(rg_id * 64 + rt * 16 + c15, h * 4 + q)];

    float vmin[16];
    float thr_reg[16];
#pragma unroll
    for (int i = 0; i < 16; ++i) vmin[i] = 3.402823466e38f;
    if (PASS == 1) {
#pragma unroll
        for (int rt = 0; rt < 4; ++rt)
#pragma unroll
            for (int rg = 0; rg < 4; ++rg)
                thr_reg[rt * 4 + rg] = thr_l[rg_id * 64 + rt * 16 + q * 4 + rg];
    }

    // Wave-owned 512 codes streamed from L2, no barriers, PF-deep ring.
#pragma unroll
    for (int cg = 0; cg < 32; ++cg) {
        const int sl = cg & (PF - 1);
        bf16x8 b0 = pb0[sl], b1 = pb1[sl];
        float  Ev = pE[sl];
        if (cg + PF < 32) {
            pb0[sl] = bp[(cg + PF) * 128];
            pb1[sl] = bp[(cg + PF) * 128 + 4];
            pE[sl]  = evp[(cg + PF) * 16];
        }
#pragma unroll
        for (int rt = 0; rt < 4; ++rt) {
            f32x4 acc = {0.f, 0.f, 0.f, 0.f};
            acc = __builtin_amdgcn_mfma_f32_16x16x32_bf16(af[rt][0], b0, acc, 0, 0, 0);
            acc = __builtin_amdgcn_mfma_f32_16x16x32_bf16(af[rt][1], b1, acc, 0, 0, 0);
#pragma unroll
            for (int rg = 0; rg < 4; ++rg) {
                float t = __builtin_fmaf(acc[rg], -2.0f, Ev);
                if (PASS == 0) {
                    vmin[rt * 4 + rg] = fminf(vmin[rt * 4 + rg], t);
                } else {
                    if (t <= thr_reg[rt * 4 + rg]) {
                        int pixel = pixbase + rg_id * 64 + rt * 16 + q * 4 + rg;
                        int code  = code0 + cg * 16 + c15;
                        u32 entry = ((u32)pixel << 13) | (u32)code;
                        u32 pos = atomicAdd(&loc_cnt, 1u);      // LDS ticket
                        if (pos < LOCBUF) {
                            loc_list[pos] = entry;
                        } else {                                // ~never
                            u32 g = atomicAdd(count, 1u);
                            if (g < CAP) list[g] = entry;
                        }
                    }
                }
            }
        }
    }

    if (PASS == 0) {
        // Reduce over the 16 code-columns, then LDS combine, then plain store.
#pragma unroll
        for (int i = 0; i < 16; ++i) {
            float v = vmin[i];
            v = fminf(v, __shfl_xor(v, 1));
            v = fminf(v, __shfl_xor(v, 2));
            v = fminf(v, __shfl_xor(v, 4));
            v = fminf(v, __shfl_xor(v, 8));
            if (c15 == 0) {
                int row = rg_id * 64 + (i >> 2) * 16 + q * 4 + (i & 3);
                atomicMin(&cm_l[row], encf(v));    // LDS atomic, cheap
            }
        }
        __syncthreads();
        if (tid < M_BLK)
            cmin8[blockIdx.y * N_PIX + pixbase + tid] = cm_l[tid];
    } else {
        // Block-level flush: one global ticket, coalesced list writes.
        __syncthreads();
        u32 n_loc = loc_cnt; if (n_loc > LOCBUF) n_loc = LOCBUF;
        if (tid == 0) glob_base = atomicAdd(count, n_loc);
        __syncthreads();
        u32 base = glob_base;
        for (u32 i = tid; i < n_loc; i += 256u) {
            u32 g = base + i;
            if (g < CAP) list[g] = loc_list[i];
        }
    }
}

// Exact refine: bit-identical reference distance chain per candidate pair.
__global__ __launch_bounds__(256) void k_refine(const float* __restrict__ z,
                                                const float* __restrict__ emb,
                                                const float* __restrict__ Sarr,
                                                const float* __restrict__ Etab,
                                                const u32* __restrict__ count,
                                                const u32* __restrict__ list,
                                                u64* __restrict__ best) {
    u32 cnt = *count; if (cnt > CAP) cnt = CAP;
    for (u32 i = blockIdx.x * 256 + threadIdx.x; i < cnt; i += 256u * 256u) {
        u32 e = list[i];
        int pixel = (int)(e >> 13), code = (int)(e & 8191u);
        const float* zp = z + (pixel >> 12) * BHW + (pixel & 4095);
        const float* ep = emb + code * C_DIM;
        float dot = 0.0f;
#pragma unroll
        for (int c = 0; c < C_DIM; ++c)
            dot = __builtin_fmaf(zp[c * HW], ep[c], dot);
        float dist = __fsub_rn(__fadd_rn(Sarr[pixel], Etab[code]),
                               __fmul_rn(2.0f, dot));
        u64 key = ((u64)__float_as_uint(dist) << 32) | (u32)code;  // dist > 0
        atomicMin(&best[pixel], key);
    }
}

// Gather z_q, write idx + z_q_st (NCHW); f64 loss via global atomicAdd,
// last-finishing block (done-counter) writes out[0] — k_loss folded in.
__global__ __launch_bounds__(256) void k_final(const float* __restrict__ z,
                                               const float* __restrict__ emb,
                                               const u64* __restrict__ best,
                                               float* __restrict__ out,
                                               double* __restrict__ loss_acc,
                                               u32* __restrict__ done) {
    const int n  = blockIdx.x * 256 + threadIdx.x;
    const int b  = n >> 12;
    const int hw = n & 4095;
    const u32 m  = (u32)(best[n] & 0xFFFFFFFFull);
    out[OUT_IDX_OFF + n] = (float)m;

    const float* zp = z + b * BHW + hw;
    const float* e  = emb + m * C_DIM;
    double lacc = 0.0;
#pragma unroll
    for (int c = 0; c < 64; ++c) {
        float zz   = zp[c * HW];
        float ec   = e[c];
        float diff = __fsub_rn(ec, zz);
        float outv = __fadd_rn(zz, diff);
        out[OUT_ZQ_OFF + b * BHW + c * HW + hw] = outv;
        lacc += (double)__fmul_rn(diff, diff);
    }
    __shared__ double sh[256];
    sh[threadIdx.x] = lacc;
    __syncthreads();
#pragma unroll
    for (int s = 128; s > 0; s >>= 1) {
        if (threadIdx.x < s) sh[threadIdx.x] += sh[threadIdx.x + s];
        __syncthreads();
    }
    if (threadIdx.x == 0) {
        atomicAdd(loss_acc, sh[0]);                 // device-scope f64 add
        __threadfence();
        u32 d = atomicAdd(done, 1u);
        if (d == (N_PIX / 256) - 1) {               // last block
            double s = atomicAdd(loss_acc, 0.0);    // atomic read of full sum
            float m1 = (float)(s / (double)ZQ_N);
            out[0] = __fadd_rn(m1, __fmul_rn(0.25f, m1));
        }
    }
}

extern "C" void kernel_launch(void* const* d_in, const int* in_sizes, int n_in,
                              void* d_out, int out_size, void* d_ws, size_t ws_size,
                              hipStream_t stream) {
    const float* z   = (const float*)d_in[0];
    const float* emb = (const float*)d_in[1];
    float* out = (float*)d_out;

    char* ws = (char*)d_ws;
    u64*    best  = (u64*)ws;
    float*  Etab  = (float*)(ws + WS_E_OFF);
    u32*    count = (u32*)(ws + WS_C_OFF);
    u32*    done  = (u32*)(ws + WS_D_OFF);
    double* lacc  = (double*)(ws + WS_A_OFF);

    float* SCR = out + 4;                       // 16B-aligned scratch in zq region
    u32*   zh    = (u32*)(SCR + OFF_ZH);
    u32*   eh    = (u32*)(SCR + OFF_EH);
    float* Sarr  = SCR + OFF_S;
    float* Wp    = SCR + OFF_W;
    u32*   cmin8 = (u32*)(SCR + OFF_CMIN8);
    u32*   list  = (u32*)(SCR + OFF_LIST);

    k_prep_z<<<dim3(N_PIX / 256), dim3(256), 0, stream>>>(z, zh, Sarr, Wp,
                                                          best, count, done, lacc);
    k_prep_e<<<dim3(NE / 256),    dim3(256), 0, stream>>>(emb, eh, Etab);
    k_gemm<0><<<dim3(N_PIX / M_BLK, NE / N_SLICE), dim3(256), 0, stream>>>(
        (const uint4*)zh, (const bf16x8*)eh, Etab, Wp, cmin8, count, list);
    k_gemm<1><<<dim3(N_PIX / M_BLK, NE / N_SLICE), dim3(256), 0, stream>>>(
        (const uint4*)zh, (const bf16x8*)eh, Etab, Wp, cmin8, count, list);
    k_refine<<<dim3(256), dim3(256), 0, stream>>>(z, emb, Sarr, Etab, count, list, best);
    k_final <<<dim3(N_PIX / 256), dim3(256), 0, stream>>>(z, emb, best, out, lacc, done);
}

// Round 9
// 241.732 us; speedup vs baseline: 3.7716x; 3.7716x over previous
//
#include <hip/hip_runtime.h>

typedef unsigned int u32;
typedef unsigned long long u64;
typedef __bf16 bf16x8 __attribute__((ext_vector_type(8)));
typedef float f32x4 __attribute__((ext_vector_type(4)));

// Problem constants
#define N_PIX   32768        // 8*64*64 pixels
#define C_DIM   64
#define NE      8192
#define HW      4096         // 64*64
#define BHW     262144       // elements per batch in z (64*4096)
#define ZQ_N    2097152      // 8*64*64*64

// Output layout (flat f32): [0]=loss, [1..2097152]=z_q_out(NCHW), [2097153..]=idx
#define OUT_ZQ_OFF  1
#define OUT_IDX_OFF (1 + ZQ_N)

// Scratch inside d_out's zq region (overwritten by k_final at the end).
// SCR = out + 4 floats (16B aligned). Offsets in 4-byte slots relative to SCR:
#define OFF_ZH    0         // u32[1048576]  : zh bf16 pairs, [pixel][feat]
#define OFF_EH    1048576   // u32[262144]   : eh bf16 pairs, [code][feat]
#define OFF_S     1310720   // f32[32768]    : ||z||^2 exact pairwise
#define OFF_W     1343488   // f32[32768]    : refine window per pixel
#define OFF_CMIN8 1376256   // u32[8*32768]  : per-slice order-encoded coarse min
#define OFF_LIST  1638400   // u32[CAP]      : candidate (pixel<<13|code)
#define CAP       458744

// Workspace (ws) layout:
#define WS_E_OFF  262144   // f32 Etab[8192] after u64 best[32768]
#define WS_C_OFF  294912   // u32 count
#define WS_D_OFF  294916   // u32 done (k_final last-block counter)
#define WS_A_OFF  294920   // f64 loss_acc

// GEMM tiling: block = 256 thr = 4 waves = 2 row-groups x 2 code-groups.
// Each wave: 64 pixel-rows (A register-resident), 512 codes streamed from L2.
#define M_BLK    128
#define N_SLICE  1024
#define N_SLICES 8         // NE / N_SLICE
#define LOCBUF   1024      // per-block candidate staging (expected ~30/block)

__device__ __forceinline__ u32 encf(float v) {
    u32 u = __float_as_uint(v);
    return (u & 0x80000000u) ? ~u : (u | 0x80000000u);
}
__device__ __forceinline__ float decf(u32 k) {
    return (k & 0x80000000u) ? __uint_as_float(k ^ 0x80000000u)
                             : __uint_as_float(~k);
}
__device__ __forceinline__ u32 bf16rn(float v) {      // RNE f32->bf16 bits
    u32 u = __float_as_uint(v);
    return (u + 0x7FFFu + ((u >> 16) & 1u)) >> 16;
}

// Fused prep: blocks [0,128) process z (pixels), blocks [128,160) process emb.
// z-part also does all one-time inits (best, count/done/loss_acc).
__global__ __launch_bounds__(256) void k_prep(const float* __restrict__ z,
                                              const float* __restrict__ emb,
                                              u32* __restrict__ zh,
                                              u32* __restrict__ eh,
                                              float* __restrict__ Sarr,
                                              float* __restrict__ Wp,
                                              float* __restrict__ Etab,
                                              u64* __restrict__ best,
                                              u32* __restrict__ count,
                                              u32* __restrict__ done,
                                              double* __restrict__ loss_acc) {
    __shared__ u32 lw[256 * 33];
    const int tid = threadIdx.x;
    if (blockIdx.x < N_PIX / 256) {
        const int p = blockIdx.x * 256 + tid;
        best[p] = ~0ull;
        if (blockIdx.x == 0 && tid == 0) { *count = 0u; *done = 0u; *loss_acc = 0.0; }
        const float* zp = z + (p >> 12) * BHW + (p & 4095);
        float r[8]; float asum = 0.0f; u32 prev = 0;
#pragma unroll
        for (int c = 0; c < C_DIM; ++c) {
            float v  = zp[c * HW];                    // coalesced
            float sq = __fmul_rn(v, v);
            if (c < 8) r[c] = sq; else r[c & 7] = __fadd_rn(r[c & 7], sq);
            asum += fabsf(v);
            u32 hb = bf16rn(v);
            if (c & 1) lw[tid * 33 + (c >> 1)] = prev | (hb << 16);
            else       prev = hb;
        }
        Sarr[p] = __fadd_rn(__fadd_rn(__fadd_rn(r[0], r[1]), __fadd_rn(r[2], r[3])),
                            __fadd_rn(__fadd_rn(r[4], r[5]), __fadd_rn(r[6], r[7])));
        // window: bf16-dot bound (slope 3x margin) + E_max(6.4e-5) + ref-rounding
        Wp[p] = 5.0e-5f * asum + 2.5e-4f;
        __syncthreads();
#pragma unroll
        for (int j = 0; j < 32; ++j) {                // coalesced u32 writes
            int lg = j * 256 + tid;
            zh[blockIdx.x * 8192 + lg] = lw[(lg >> 5) * 33 + (lg & 31)];
        }
    } else {
        const int mb = blockIdx.x - N_PIX / 256;
        const int m  = mb * 256 + tid;
        const float* rp = emb + m * C_DIM;
        float r[8]; u32 prev = 0;
#pragma unroll
        for (int c = 0; c < C_DIM; ++c) {
            float v  = rp[c];
            float sq = __fmul_rn(v, v);
            if (c < 8) r[c] = sq; else r[c & 7] = __fadd_rn(r[c & 7], sq);
            u32 hb = bf16rn(v);
            if (c & 1) lw[tid * 33 + (c >> 1)] = prev | (hb << 16);
            else       prev = hb;
        }
        Etab[m] = __fadd_rn(__fadd_rn(__fadd_rn(r[0], r[1]), __fadd_rn(r[2], r[3])),
                            __fadd_rn(__fadd_rn(r[4], r[5]), __fadd_rn(r[6], r[7])));
        __syncthreads();
#pragma unroll
        for (int j = 0; j < 32; ++j) {
            int lg = j * 256 + tid;
            eh[mb * 8192 + lg] = lw[(lg >> 5) * 33 + (lg & 31)];
        }
    }
}

// Coarse GEMM. Score = acc = zh.eh (bf16 MFMA); min dist <=> max acc
// (||e||^2 dropped from the coarse score, absorbed into Wp — kills the Ev
// load + fmaf per element). A fragments loaded DIRECTLY global->VGPR (no
// LDS copy => compiler cannot rematerialize via ds_read; round-6/7 lesson).
// B: named-variable depth-2 ping-pong (round-8 lesson: runtime-indexed local
// arrays spill to scratch => 2.4 GB HBM traffic). amdgpu_waves_per_eu(4,4)
// pins the allocator at 128 VGPRs so af/vmax/prefetch stay resident.
// PASS 0: per-pixel max(acc) -> LDS -> plain store cmin8[slice][pixel] (encf(-2*max)).
// PASS 1: thr = decf(min8 of cmin8) + Wp; collect acc >= -thr/2 via LDS
//         staging, one global ticket per block (round-4 lesson).
#define GEMM_STEP(CG, B0, B1)                                                   \
    {                                                                           \
        _Pragma("unroll")                                                       \
        for (int rt = 0; rt < 4; ++rt) {                                        \
            f32x4 acc = {0.f, 0.f, 0.f, 0.f};                                   \
            acc = __builtin_amdgcn_mfma_f32_16x16x32_bf16(af[rt][0], B0, acc, 0, 0, 0); \
            acc = __builtin_amdgcn_mfma_f32_16x16x32_bf16(af[rt][1], B1, acc, 0, 0, 0); \
            _Pragma("unroll")                                                   \
            for (int rg = 0; rg < 4; ++rg) {                                    \
                if (PASS == 0) {                                                \
                    vmax[rt * 4 + rg] = fmaxf(vmax[rt * 4 + rg], acc[rg]);      \
                } else {                                                        \
                    if (acc[rg] >= nthr[rt * 4 + rg]) {                         \
                        int pixel = pixbase + rg_id * 64 + rt * 16 + q * 4 + rg;\
                        int code  = code0 + (CG) * 16 + c15;                    \
                        u32 entry = ((u32)pixel << 13) | (u32)code;             \
                        u32 pos = atomicAdd(&loc_cnt, 1u);                      \
                        if (pos < LOCBUF) loc_list[pos] = entry;                \
                        else { u32 g = atomicAdd(count, 1u);                    \
                               if (g < CAP) list[g] = entry; }                  \
                    }                                                           \
                }                                                               \
            }                                                                   \
        }                                                                       \
    }

template <int PASS>
__global__ __launch_bounds__(256)
__attribute__((amdgpu_waves_per_eu(4, 4)))
void k_gemm(const bf16x8* __restrict__ zh8,
            const bf16x8* __restrict__ eh8,
            const float* __restrict__ Wp,
            u32* __restrict__ cmin8,
            u32* __restrict__ count,
            u32* __restrict__ list) {
    __shared__ u32  cm_l[M_BLK];         // pass-0 block-local min (encoded)
    __shared__ float thr_l[M_BLK];       // pass-1 raw thresholds
    __shared__ u32 loc_list[LOCBUF];     // 4 KB pass-1 candidate staging
    __shared__ u32 loc_cnt, glob_base;

    const int tid  = threadIdx.x;
    const int lane = tid & 63, w = tid >> 6;
    const int rg_id = w & 1;             // row-group: 64 rows each
    const int cg_id = w >> 1;            // code-group: 512 codes each
    const int q = lane >> 4, c15 = lane & 15;
    const int pixbase   = blockIdx.x * M_BLK;
    const int slicebase = blockIdx.y * N_SLICE;
    const int code0     = slicebase + cg_id * 512;

    // B prefetch ring (named vars only), issued first.
    const bf16x8* bpl = eh8 + (size_t)(code0 + c15) * 8 + q;
    bf16x8 n0a = bpl[0],   n1a = bpl[4];      // cg+0
    bf16x8 n0b = bpl[128], n1b = bpl[132];    // cg+1

    // A fragments straight from global (L2-hot, 8 x 16B per thread).
    const bf16x8* apl = zh8 + (size_t)(pixbase + rg_id * 64 + c15) * 8 + q;
    bf16x8 af[4][2];
#pragma unroll
    for (int rt = 0; rt < 4; ++rt) {
        af[rt][0] = apl[rt * 128];
        af[rt][1] = apl[rt * 128 + 4];
    }

    if (PASS == 0 && tid < M_BLK) cm_l[tid] = 0xFFFFFFFFu;
    if (PASS == 1) {
        if (tid < M_BLK) {
            u32 mn = 0xFFFFFFFFu;
#pragma unroll
            for (int s = 0; s < N_SLICES; ++s)
                mn = min(mn, cmin8[s * N_PIX + pixbase + tid]);  // encoded: u32 min ok
            thr_l[tid] = decf(mn) + Wp[pixbase + tid];
        }
        if (tid == 0) loc_cnt = 0u;
        __syncthreads();
    }

    float vmax[16];
    float nthr[16];
#pragma unroll
    for (int i = 0; i < 16; ++i) vmax[i] = -3.402823466e38f;
    if (PASS == 1) {
#pragma unroll
        for (int rt = 0; rt < 4; ++rt)
#pragma unroll
            for (int rg = 0; rg < 4; ++rg)   // acc >= -thr/2  <=>  -2acc <= thr
                nthr[rt * 4 + rg] = -0.5f * thr_l[rg_id * 64 + rt * 16 + q * 4 + rg];
    }

    // 512 codes, barrier-free, depth-2 ping-pong.
#pragma unroll 2
    for (int cg = 0; cg < 32; cg += 2) {
        bf16x8 c0 = n0a, c1 = n1a;
        if (cg + 2 < 32) { n0a = bpl[(cg + 2) * 128]; n1a = bpl[(cg + 2) * 128 + 4]; }
        GEMM_STEP(cg, c0, c1);
        bf16x8 d0 = n0b, d1 = n1b;
        if (cg + 3 < 32) { n0b = bpl[(cg + 3) * 128]; n1b = bpl[(cg + 3) * 128 + 4]; }
        GEMM_STEP(cg + 1, d0, d1);
    }

    if (PASS == 0) {
        // Reduce the 16 code-columns per row, LDS-combine, plain store.
#pragma unroll
        for (int i = 0; i < 16; ++i) {
            float v = vmax[i];
            v = fmaxf(v, __shfl_xor(v, 1));
            v = fmaxf(v, __shfl_xor(v, 2));
            v = fmaxf(v, __shfl_xor(v, 4));
            v = fmaxf(v, __shfl_xor(v, 8));
            if (c15 == 0) {
                int row = rg_id * 64 + (i >> 2) * 16 + q * 4 + (i & 3);
                atomicMin(&cm_l[row], encf(-2.0f * v));   // LDS atomic, cheap
            }
        }
        __syncthreads();
        if (tid < M_BLK)
            cmin8[blockIdx.y * N_PIX + pixbase + tid] = cm_l[tid];
    } else {
        // Block-level flush: one global ticket, coalesced list writes.
        __syncthreads();
        u32 n_loc = loc_cnt; if (n_loc > LOCBUF) n_loc = LOCBUF;
        if (tid == 0) glob_base = atomicAdd(count, n_loc);
        __syncthreads();
        u32 base = glob_base;
        for (u32 i = tid; i < n_loc; i += 256u) {
            u32 g = base + i;
            if (g < CAP) list[g] = loc_list[i];
        }
    }
}

// Exact refine: bit-identical reference distance chain per candidate pair.
__global__ __launch_bounds__(256) void k_refine(const float* __restrict__ z,
                                                const float* __restrict__ emb,
                                                const float* __restrict__ Sarr,
                                                const float* __restrict__ Etab,
                                                const u32* __restrict__ count,
                                                const u32* __restrict__ list,
                                                u64* __restrict__ best) {
    u32 cnt = *count; if (cnt > CAP) cnt = CAP;
    for (u32 i = blockIdx.x * 256 + threadIdx.x; i < cnt; i += 256u * 256u) {
        u32 e = list[i];
        int pixel = (int)(e >> 13), code = (int)(e & 8191u);
        const float* zp = z + (pixel >> 12) * BHW + (pixel & 4095);
        const float* ep = emb + code * C_DIM;
        float dot = 0.0f;
#pragma unroll
        for (int c = 0; c < C_DIM; ++c)
            dot = __builtin_fmaf(zp[c * HW], ep[c], dot);
        float dist = __fsub_rn(__fadd_rn(Sarr[pixel], Etab[code]),
                               __fmul_rn(2.0f, dot));
        u64 key = ((u64)__float_as_uint(dist) << 32) | (u32)code;  // dist > 0
        atomicMin(&best[pixel], key);
    }
}

// Gather z_q, write idx + z_q_st (NCHW); f64 loss via global atomicAdd,
// last-finishing block (done-counter) writes out[0].
__global__ __launch_bounds__(256) void k_final(const float* __restrict__ z,
                                               const float* __restrict__ emb,
                                               const u64* __restrict__ best,
                                               float* __restrict__ out,
                                               double* __restrict__ loss_acc,
                                               u32* __restrict__ done) {
    const int n  = blockIdx.x * 256 + threadIdx.x;
    const int b  = n >> 12;
    const int hw = n & 4095;
    const u32 m  = (u32)(best[n] & 0xFFFFFFFFull);
    out[OUT_IDX_OFF + n] = (float)m;

    const float* zp = z + b * BHW + hw;
    const float* e  = emb + m * C_DIM;
    double lacc = 0.0;
#pragma unroll
    for (int c = 0; c < 64; ++c) {
        float zz   = zp[c * HW];
        float ec   = e[c];
        float diff = __fsub_rn(ec, zz);
        float outv = __fadd_rn(zz, diff);
        out[OUT_ZQ_OFF + b * BHW + c * HW + hw] = outv;
        lacc += (double)__fmul_rn(diff, diff);
    }
    __shared__ double sh[256];
    sh[threadIdx.x] = lacc;
    __syncthreads();
#pragma unroll
    for (int s = 128; s > 0; s >>= 1) {
        if (threadIdx.x < s) sh[threadIdx.x] += sh[threadIdx.x + s];
        __syncthreads();
    }
    if (threadIdx.x == 0) {
        atomicAdd(loss_acc, sh[0]);                 // device-scope f64 add
        __threadfence();
        u32 d = atomicAdd(done, 1u);
        if (d == (N_PIX / 256) - 1) {               // last block
            double s = atomicAdd(loss_acc, 0.0);    // atomic read of full sum
            float m1 = (float)(s / (double)ZQ_N);
            out[0] = __fadd_rn(m1, __fmul_rn(0.25f, m1));
        }
    }
}

extern "C" void kernel_launch(void* const* d_in, const int* in_sizes, int n_in,
                              void* d_out, int out_size, void* d_ws, size_t ws_size,
                              hipStream_t stream) {
    const float* z   = (const float*)d_in[0];
    const float* emb = (const float*)d_in[1];
    float* out = (float*)d_out;

    char* ws = (char*)d_ws;
    u64*    best  = (u64*)ws;
    float*  Etab  = (float*)(ws + WS_E_OFF);
    u32*    count = (u32*)(ws + WS_C_OFF);
    u32*    done  = (u32*)(ws + WS_D_OFF);
    double* lacc  = (double*)(ws + WS_A_OFF);

    float* SCR = out + 4;                       // 16B-aligned scratch in zq region
    u32*   zh    = (u32*)(SCR + OFF_ZH);
    u32*   eh    = (u32*)(SCR + OFF_EH);
    float* Sarr  = SCR + OFF_S;
    float* Wp    = SCR + OFF_W;
    u32*   cmin8 = (u32*)(SCR + OFF_CMIN8);
    u32*   list  = (u32*)(SCR + OFF_LIST);

    k_prep<<<dim3(N_PIX / 256 + NE / 256), dim3(256), 0, stream>>>(
        z, emb, zh, eh, Sarr, Wp, Etab, best, count, done, lacc);
    k_gemm<0><<<dim3(N_PIX / M_BLK, N_SLICES), dim3(256), 0, stream>>>(
        (const bf16x8*)zh, (const bf16x8*)eh, Wp, cmin8, count, list);
    k_gemm<1><<<dim3(N_PIX / M_BLK, N_SLICES), dim3(256), 0, stream>>>(
        (const bf16x8*)zh, (const bf16x8*)eh, Wp, cmin8, count, list);
    k_refine<<<dim3(256), dim3(256), 0, stream>>>(z, emb, Sarr, Etab, count, list, best);
    k_final <<<dim3(N_PIX / 256), dim3(256), 0, stream>>>(z, emb, best, out, lacc, done);
}